// Round 4
// baseline (7004.714 us; speedup 1.0000x reference)
//
#include <hip/hip_runtime.h>

typedef unsigned short u16;
typedef __attribute__((ext_vector_type(8))) __bf16 bf16x8;
typedef __attribute__((ext_vector_type(4))) float f32x4;
typedef __attribute__((ext_vector_type(4))) unsigned int u32x4;
typedef __attribute__((ext_vector_type(2))) unsigned int u32x2;

// ---------- workspace layout (bytes) ----------
#define GX_OFF   0ull                      // gates_x [32768][1024][4] bf16 = 268435456
#define FT_OFF   268435456ull              // ft      [32768][1024]    bf16 = 67108864
#define WT_OFF   335544320ull              // Wt      [4096][2048]     bf16 = 16777216
#define W1T_OFF  352321536ull              // W1t     [2048][256]      bf16 = 1048576 (dead after k_field)
#define CB_OFF   352321536ull              // cbuf [64][1024] f32 = 262144  (overlays W1t)
#define HF_OFF   352583680ull              // hfin [64][1024] f32 = 262144  (overlays W1t)
#define HB_OFF   353370112ull              // hbuf [2][64][1024] bf16 = 262144
#define WS_NEED  (HB_OFF + 262144ull)      // = 353632256, <= round-1-proven ws size

__device__ __forceinline__ float b2f(u16 u) {
    unsigned x = ((unsigned)u) << 16;
    return __builtin_bit_cast(float, x);
}
__device__ __forceinline__ u16 f2b(float f) {   // rne f32->bf16
    unsigned u = __builtin_bit_cast(unsigned, f);
    unsigned r = (u + 0x7FFFu + ((u >> 16) & 1u)) >> 16;
    return (u16)r;
}
__device__ __forceinline__ float fsigm(float x) {
    return __builtin_amdgcn_rcpf(1.f + __expf(-x));
}
__device__ __forceinline__ float ftanh2(float x) {
    return 2.f * __builtin_amdgcn_rcpf(1.f + __expf(-2.f * x)) - 1.f;
}
__device__ __forceinline__ bf16x8 ld_frag(const u16* p) {
    u32x4 v = *(const u32x4*)p;
    return __builtin_bit_cast(bf16x8, v);
}
__device__ __forceinline__ f32x4 mfma16(bf16x8 a, bf16x8 b, f32x4 c) {
    return __builtin_amdgcn_mfma_f32_16x16x32_bf16(a, b, c, 0, 0, 0);
}
// load 8 f32, convert to 8 bf16 packed in u32x4
__device__ __forceinline__ u32x4 cvt8(const float* p) {
    f32x4 a = *(const f32x4*)p;
    f32x4 b = *(const f32x4*)(p + 4);
    u32x4 r;
    r.x = (unsigned)f2b(a[0]) | ((unsigned)f2b(a[1]) << 16);
    r.y = (unsigned)f2b(a[2]) | ((unsigned)f2b(a[3]) << 16);
    r.z = (unsigned)f2b(b[0]) | ((unsigned)f2b(b[1]) << 16);
    r.w = (unsigned)f2b(b[2]) | ((unsigned)f2b(b[3]) << 16);
    return r;
}

// ---------- transpose+cast: out_bf16[c][r] = f2b(in_f32[r][c]) ----------
__global__ void k_transpose(const float* __restrict__ in, u16* __restrict__ out, int R, int C) {
    __shared__ u16 tl[64][65];
    int tx = threadIdx.x, ty = threadIdx.y;
    int c0 = blockIdx.x * 64, r0 = blockIdx.y * 64;
#pragma unroll
    for (int i = 0; i < 16; i++) {
        int a = ty + i * 4;
        tl[a][tx] = f2b(in[(size_t)(r0 + a) * C + c0 + tx]);
    }
    __syncthreads();
#pragma unroll
    for (int i = 0; i < 16; i++) {
        int a = ty + i * 4;
        out[(size_t)(c0 + a) * R + r0 + tx] = tl[tx][a];
    }
}

// ---------- field GEMM: ft = sigmoid(F@W1[:, :1024]+b) * tanh(F@W1[:, 1024:]+b) ----------
// F is f32 (converted during staging); W1t bf16. tile 128 rows x 64 H-cols. K=256.
__global__ __launch_bounds__(256) void k_field(const float* __restrict__ F, const u16* __restrict__ W1t,
                                               const float* __restrict__ bW1,
                                               u16* __restrict__ ftw) {
    int m0 = blockIdx.y * 128;
    int n0 = blockIdx.x * 64;
    __shared__ u16 As[128 * 40];
    __shared__ u16 Bs[128 * 40];
    int tid = threadIdx.x, w = tid >> 6, lane = tid & 63, quad = lane >> 4, l16 = lane & 15;
    f32x4 acc[2][8];
#pragma unroll
    for (int mt = 0; mt < 2; mt++)
#pragma unroll
        for (int nt = 0; nt < 8; nt++) acc[mt][nt] = (f32x4){0.f, 0.f, 0.f, 0.f};

    for (int kc = 0; kc < 8; kc++) {
        __syncthreads();
#pragma unroll
        for (int it = 0; it < 2; it++) {
            int q = tid + it * 256, row = q >> 2, sub = q & 3;
            u32x4 va = cvt8(F + (size_t)(m0 + row) * 256 + kc * 32 + sub * 8);
            *(u32x4*)(As + row * 40 + sub * 8) = va;
            int brow = (row < 64) ? (n0 + row) : (1024 + n0 + row - 64);
            u32x4 vb = *(const u32x4*)(W1t + (size_t)brow * 256 + kc * 32 + sub * 8);
            *(u32x4*)(Bs + row * 40 + sub * 8) = vb;
        }
        __syncthreads();
        bf16x8 af[2], bfr[8];
#pragma unroll
        for (int mt = 0; mt < 2; mt++) af[mt] = ld_frag(As + (w * 32 + mt * 16 + l16) * 40 + quad * 8);
#pragma unroll
        for (int nt = 0; nt < 8; nt++) bfr[nt] = ld_frag(Bs + (nt * 16 + l16) * 40 + quad * 8);
#pragma unroll
        for (int mt = 0; mt < 2; mt++)
#pragma unroll
            for (int nt = 0; nt < 8; nt++) acc[mt][nt] = mfma16(af[mt], bfr[nt], acc[mt][nt]);
    }
#pragma unroll
    for (int nth = 0; nth < 4; nth++) {
        float br = bW1[n0 + nth * 16 + l16];
        float bd = bW1[1024 + n0 + nth * 16 + l16];
#pragma unroll
        for (int mt = 0; mt < 2; mt++) {
#pragma unroll
            for (int j = 0; j < 4; j++) {
                int r = m0 + w * 32 + mt * 16 + quad * 4 + j;
                float rv = acc[mt][nth][j] + br;
                float dv = acc[mt][nth + 4][j] + bd;
                ftw[(size_t)r * 1024 + n0 + nth * 16 + l16] = f2b(fsigm(rv) * ftanh2(dv));
            }
        }
    }
}

// ---------- x GEMM: gx[r][H][g] = X@W[:1024,:] + bW (gate-interleaved, bf16 store) ----------
// X f32 (converted during staging); Wt bf16. tile 128x128, K=1024.
__global__ __launch_bounds__(256) void k_xgemm(const float* __restrict__ X, const u16* __restrict__ Wt,
                                               const float* __restrict__ bWv,
                                               u16* __restrict__ gx) {
    int m0 = blockIdx.y * 128;
    int n0 = blockIdx.x * 128;
    __shared__ u16 As[128 * 40];
    __shared__ u16 Bs[128 * 40];
    int tid = threadIdx.x, w = tid >> 6, lane = tid & 63, quad = lane >> 4, l16 = lane & 15;
    int mq = (w & 1) * 64, nq = (w >> 1) * 64;
    f32x4 acc[4][4];
#pragma unroll
    for (int mt = 0; mt < 4; mt++)
#pragma unroll
        for (int nt = 0; nt < 4; nt++) acc[mt][nt] = (f32x4){0.f, 0.f, 0.f, 0.f};

    for (int kc = 0; kc < 32; kc++) {
        __syncthreads();
#pragma unroll
        for (int it = 0; it < 2; it++) {
            int q = tid + it * 256, row = q >> 2, sub = q & 3;
            u32x4 va = cvt8(X + (size_t)(m0 + row) * 1024 + kc * 32 + sub * 8);
            *(u32x4*)(As + row * 40 + sub * 8) = va;
            u32x4 vb = *(const u32x4*)(Wt + (size_t)(n0 + row) * 2048 + kc * 32 + sub * 8);
            *(u32x4*)(Bs + row * 40 + sub * 8) = vb;
        }
        __syncthreads();
        bf16x8 af[4], bfr[4];
#pragma unroll
        for (int mt = 0; mt < 4; mt++) af[mt] = ld_frag(As + (mq + mt * 16 + l16) * 40 + quad * 8);
#pragma unroll
        for (int nt = 0; nt < 4; nt++) bfr[nt] = ld_frag(Bs + (nq + nt * 16 + l16) * 40 + quad * 8);
#pragma unroll
        for (int mt = 0; mt < 4; mt++)
#pragma unroll
            for (int nt = 0; nt < 4; nt++) acc[mt][nt] = mfma16(af[mt], bfr[nt], acc[mt][nt]);
    }
#pragma unroll
    for (int nt = 0; nt < 4; nt++) {
        int gcol = n0 + nq + nt * 16 + l16;
        int hcol = gcol & 1023, g = gcol >> 10;
        float bw = bWv[gcol];
#pragma unroll
        for (int mt = 0; mt < 4; mt++) {
#pragma unroll
            for (int j = 0; j < 4; j++) {
                int r = m0 + mq + mt * 16 + quad * 4 + j;
                gx[(size_t)r * 4096 + hcol * 4 + g] = f2b(acc[mt][nt][j] + bw);
            }
        }
    }
}

// ---------- zero-init recurrent state ----------
__global__ void k_zero(u16* __restrict__ hbuf, float* __restrict__ cbuf, float* __restrict__ hfin) {
    int idx = blockIdx.x * 1024 + threadIdx.x;  // 64k threads
    hbuf[idx] = 0; hbuf[65536 + idx] = 0;
    cbuf[idx] = 0.f; hfin[idx] = 0.f;
}

// ---------- one LSTM time-step (512 sequential launches; stream order = sync) ----------
__global__ __launch_bounds__(256) void k_step(const u16* __restrict__ Wt, const u16* __restrict__ gx,
                                              const u16* __restrict__ ftw, const int* __restrict__ len,
                                              float* __restrict__ out, u16* __restrict__ hbuf,
                                              float* __restrict__ cbuf, float* __restrict__ hfin, int t) {
    int wg = blockIdx.x;
    int tid = threadIdx.x, w = tid >> 6, lane = tid & 63, quad = lane >> 4, l16 = lane & 15;
    __shared__ float red[4 * 64 * 68];  // [wave][c][row(+pad)]

    const u16* hb = hbuf + (t & 1) * 65536;
    u16* hbn = hbuf + ((t + 1) & 1) * 65536;

    f32x4 acc[4][4];
#pragma unroll
    for (int mt = 0; mt < 4; mt++)
#pragma unroll
        for (int nt = 0; nt < 4; nt++) acc[mt][nt] = (f32x4){0.f, 0.f, 0.f, 0.f};

#pragma unroll
    for (int kk = 0; kk < 8; kk++) {
        bf16x8 af[4], bq[4];
#pragma unroll
        for (int mt = 0; mt < 4; mt++)
            af[mt] = ld_frag(hb + (mt * 16 + l16) * 1024 + w * 256 + kk * 32 + quad * 8);
#pragma unroll
        for (int nt = 0; nt < 4; nt++) {
            int c = nt * 16 + l16;
            int gcol = (c & 3) * 1024 + wg * 16 + (c >> 2);
            bq[nt] = ld_frag(Wt + (size_t)gcol * 2048 + 1024 + w * 256 + kk * 32 + quad * 8);
        }
#pragma unroll
        for (int mt = 0; mt < 4; mt++)
#pragma unroll
            for (int nt = 0; nt < 4; nt++) acc[mt][nt] = mfma16(af[mt], bq[nt], acc[mt][nt]);
    }

#pragma unroll
    for (int mt = 0; mt < 4; mt++)
#pragma unroll
        for (int nt = 0; nt < 4; nt++)
            *(f32x4*)&red[(w * 64 + nt * 16 + l16) * 68 + mt * 16 + quad * 4] = acc[mt][nt];
    __syncthreads();

    int hc = tid & 15, rg = tid >> 4;
    int Hcol = wg * 16 + hc;
    f32x4 Gv[4];
#pragma unroll
    for (int g = 0; g < 4; g++) {
        int c = hc * 4 + g;
        f32x4 s = *(f32x4*)&red[(0 * 64 + c) * 68 + rg * 4];
#pragma unroll
        for (int wq = 1; wq < 4; wq++) s += *(f32x4*)&red[(wq * 64 + c) * 68 + rg * 4];
        Gv[g] = s;
    }

#pragma unroll
    for (int j = 0; j < 4; j++) {
        int bb = rg * 4 + j;
        size_t rowi = (size_t)bb * 512 + t;
        u32x2 gq = *(const u32x2*)(gx + rowi * 4096 + (size_t)Hcol * 4);
        float iv = Gv[0][j] + b2f((u16)(gq.x & 0xffff));
        float jv = Gv[1][j] + b2f((u16)(gq.x >> 16));
        float fv = Gv[2][j] + b2f((u16)(gq.y & 0xffff));
        float ov = Gv[3][j] + b2f((u16)(gq.y >> 16));
        float ftv = b2f(ftw[rowi * 1024 + Hcol]);
        float cprev = cbuf[bb * 1024 + Hcol];
        float hprev = hfin[bb * 1024 + Hcol];
        float cn = fsigm(fv + 1.f) * cprev + fsigm(iv) * ftanh2(jv) + ftv;
        float hn = fsigm(ov) * ftanh2(cn);
        bool act = t < len[bb];
        out[(size_t)bb * 524288 + (size_t)t * 1024 + Hcol] = act ? hn : 0.f;
        hbn[bb * 1024 + Hcol] = f2b(act ? hn : hprev);
        cbuf[bb * 1024 + Hcol] = act ? cn : cprev;
        hfin[bb * 1024 + Hcol] = act ? hn : hprev;
    }
}

// ---------- final state writeout (f32) ----------
__global__ void k_fin(const float* __restrict__ hfin, const float* __restrict__ cbuf,
                      float* __restrict__ out) {
    int idx = blockIdx.x * 1024 + threadIdx.x;  // 65536
    out[33554432 + idx] = hfin[idx];
    out[33554432 + 65536 + idx] = cbuf[idx];
}

extern "C" void kernel_launch(void* const* d_in, const int* in_sizes, int n_in,
                              void* d_out, int out_size, void* d_ws, size_t ws_size,
                              hipStream_t stream) {
    (void)in_sizes; (void)n_in; (void)out_size;
    if (ws_size < WS_NEED) return;

    const float* X   = (const float*)d_in[0];
    const float* F   = (const float*)d_in[1];
    const int*   len = (const int*)d_in[2];
    const float* W   = (const float*)d_in[3];
    const float* bW  = (const float*)d_in[4];
    const float* W1  = (const float*)d_in[5];
    const float* bW1 = (const float*)d_in[6];
    float* out = (float*)d_out;

    char* ws = (char*)d_ws;
    u16*   gx   = (u16*)(ws + GX_OFF);
    u16*   ftw  = (u16*)(ws + FT_OFF);
    u16*   Wt   = (u16*)(ws + WT_OFF);
    u16*   W1t  = (u16*)(ws + W1T_OFF);
    float* cbuf = (float*)(ws + CB_OFF);   // overlays W1t (dead after k_field)
    float* hfin = (float*)(ws + HF_OFF);   // overlays W1t (dead after k_field)
    u16*   hbuf = (u16*)(ws + HB_OFF);

    k_transpose<<<dim3(64, 32), dim3(64, 4), 0, stream>>>(W, Wt, 2048, 4096);
    k_transpose<<<dim3(32, 4), dim3(64, 4), 0, stream>>>(W1, W1t, 256, 2048);
    k_field<<<dim3(16, 256), 256, 0, stream>>>(F, W1t, bW1, ftw);
    k_xgemm<<<dim3(32, 256), 256, 0, stream>>>(X, Wt, bW, gx);
    k_zero<<<64, 1024, 0, stream>>>(hbuf, cbuf, hfin);   // after k_field (cbuf/hfin overlay W1t)

    for (int t = 0; t < 512; t++)
        k_step<<<64, 256, 0, stream>>>(Wt, gx, ftw, len, out, hbuf, cbuf, hfin, t);

    k_fin<<<64, 1024, 0, stream>>>(hfin, cbuf, out);
}